// Round 11
// baseline (1567.159 us; speedup 1.0000x reference)
//
#include <hip/hip_runtime.h>

typedef short short8 __attribute__((ext_vector_type(8)));
typedef float f4 __attribute__((ext_vector_type(4)));

#define BATCH 128
#define SEQ   512
#define EMB   256
#define HID   256
#define G4    1024   // 4*HID

static __device__ __forceinline__ unsigned short f2b(float f) {
    union { float f; unsigned int u; } v; v.f = f;
    unsigned int u = v.u;
    return (unsigned short)((u + 0x7FFFu + ((u >> 16) & 1u)) >> 16);  // RNE
}
static __device__ __forceinline__ float b2f(unsigned short s) {
    union { unsigned int u; float f; } v; v.u = ((unsigned int)s) << 16;
    return v.f;
}

// ---------------- Kernel 0: convert weights, fold biases, zero sync state -------
__global__ void prep_kernel(const float* __restrict__ W_x, const float* __restrict__ U_h,
                            const float* __restrict__ b_x, const float* __restrict__ b_u,
                            const float* __restrict__ b_g,
                            unsigned short* __restrict__ w_xb, unsigned short* __restrict__ u_hb,
                            float* __restrict__ bias,
                            unsigned int* __restrict__ hx32, float* __restrict__ out) {
    int i = blockIdx.x * blockDim.x + threadIdx.x;
    if (i < G4 * EMB) w_xb[i] = f2b(W_x[i]);
    if (i < G4 * HID) u_hb[i] = f2b(U_h[i]);
    if (i < G4) bias[i] = b_x[i] + b_u[i] + b_g[i];
    if (i < 65536) hx32[i] = 0;      // tag=0 everywhere (re-zeroed EVERY launch)
    if (i < 256) out[i] = 0.0f;      // out is atomicAdd-accumulated
}

// ---------------- Kernel 1: xp[s][b][g] = emb[tokens[b,s]] @ W_x^T + bias --------
__global__ __launch_bounds__(256) void xp_gemm(
    const int* __restrict__ tokens, const float* __restrict__ emb,
    const unsigned short* __restrict__ w_xb, const float* __restrict__ bias,
    unsigned short* __restrict__ xp)
{
    __shared__ unsigned short As[64][264];   // A tile
    __shared__ unsigned short Bs[64][264];   // staged B slice
    __shared__ unsigned short Xs[64][72];    // store-transpose bounce
    const int m0 = blockIdx.x * 64;
    const int b  = m0 >> 9;          // m0 / SEQ
    const int s0 = m0 & 511;         // m0 % SEQ
    const int tid = threadIdx.x;
    const int cS = tid >> 2, qS = (tid & 3) * 64;   // staging map (A and B)
    {
        const int tok = tokens[m0 + cS];
        const float* src = emb + (long)tok * EMB + qS;
        #pragma unroll
        for (int i = 0; i < 8; ++i) {
            float4 v0 = ((const float4*)src)[2 * i];
            float4 v1 = ((const float4*)src)[2 * i + 1];
            short8 pk;
            pk[0] = (short)f2b(v0.x); pk[1] = (short)f2b(v0.y);
            pk[2] = (short)f2b(v0.z); pk[3] = (short)f2b(v0.w);
            pk[4] = (short)f2b(v1.x); pk[5] = (short)f2b(v1.y);
            pk[6] = (short)f2b(v1.z); pk[7] = (short)f2b(v1.w);
            *(short8*)&As[cS][qS + i * 8] = pk;
        }
    }
    __syncthreads();
    const int w = tid >> 6, l = tid & 63;
    const int ln = l & 15, hi = l >> 4;
    short8 a[8];
    #pragma unroll
    for (int kk = 0; kk < 8; ++kk)
        a[kk] = *(const short8*)&As[16 * w + ln][kk * 32 + hi * 8];

    const int rl = tid >> 2;            // global-store row (own wave's rows)
    const int cl = (tid & 3) * 16;      // global-store col offset in 64-tile

    for (int n0 = 0; n0 < G4; n0 += 64) {
        {
            const unsigned short* src = &w_xb[(size_t)(n0 + cS) * EMB + qS];
            #pragma unroll
            for (int i = 0; i < 8; ++i)
                *(short8*)&Bs[cS][qS + i * 8] = *(const short8*)&src[i * 8];
        }
        __syncthreads();
        f4 acc[4] = {};
        #pragma unroll
        for (int kk = 0; kk < 8; ++kk) {
            #pragma unroll
            for (int nn = 0; nn < 4; ++nn) {
                short8 bfr = *(const short8*)&Bs[nn * 16 + ln][kk * 32 + hi * 8];
                acc[nn] = __builtin_amdgcn_mfma_f32_16x16x32_bf16(a[kk], bfr, acc[nn], 0, 0, 0);
            }
        }
        #pragma unroll
        for (int nn = 0; nn < 4; ++nn) {
            const float bs = bias[n0 + nn * 16 + ln];
            #pragma unroll
            for (int r = 0; r < 4; ++r)
                Xs[16 * w + 4 * hi + r][nn * 16 + ln] = f2b(acc[nn][r] + bs);
        }
        size_t off = ((size_t)(s0 + rl) * BATCH + b) * G4 + n0 + cl;
        *(short8*)&xp[off]     = *(const short8*)&Xs[rl][cl];
        *(short8*)&xp[off + 8] = *(const short8*)&Xs[rl][cl + 8];
        __syncthreads();
    }
}

// ---------------- Kernel 2: LSTM, 32 blocks = 8 batch-groups x 4 unit-quarters --
// Block (g=bid&7, q=bid>>3): batch rows 16g..+16, units q*64..+64, all 4 gates.
// B-quarter (128 KB) ENTIRELY in registers: 32 frags = 128 VGPRs (256 thr, 1 wave/SIMD).
// Wave w owns units [16w,16w+16) of quarter; lane cell = (rows 4hi+r, unit w*16+ln).
// Exchange: r10 tagged-word protocol, 3 partners (same g, other q; full-graph
// mutual poll each step => publish-after-poll transitively prevents ABA).
// Own K-slices (2q,2q+1) MFMA before the wait; partner slices after copy-in.
__global__ void __launch_bounds__(256, 1)
lstm_recur(const unsigned short* __restrict__ xp,
           const unsigned short* __restrict__ u_hb,
           const float* __restrict__ fc_w, const float* __restrict__ fc_b,
           unsigned int* __restrict__ hxw, float* __restrict__ out)
{
    __shared__ unsigned short hb0[16 * 264];   // h buffers, parity 0/1 (264-us rows)
    __shared__ unsigned short hb1[16 * 264];
    __shared__ unsigned short xl0[16 * 256];   // xp tiles, parity 0/1
    __shared__ unsigned short xl1[16 * 256];
    const int tid = threadIdx.x;
    const int w = tid >> 6, l = tid & 63;
    const int ln = l & 15, hi = l >> 4;
    const int bid = blockIdx.x;
    const int g = bid & 7, q = bid >> 3;
    const int uin = w * 16 + ln;          // unit within quarter [0,64)
    const int ugl = q * 64 + uin;         // global unit

    // B regs: ALL 8 K-slices x 4 gates = 32 frags = 128 VGPRs
    short8 Br[8][4];
    #pragma unroll
    for (int s = 0; s < 8; ++s)
        #pragma unroll
        for (int gq = 0; gq < 4; ++gq) {
            const int col = gq * 256 + q * 64 + uin;
            Br[s][gq] = *(const short8*)&u_hb[(size_t)col * HID + s * 32 + hi * 8];
        }

    // zero both h buffers
    for (int i = tid; i < 2112; i += 256) { ((unsigned*)hb0)[i] = 0; ((unsigned*)hb1)[i] = 0; }

    // xp staging: thread -> (row=tid>>4, strip j>>2, 32B chunk j&3)
    const int row = tid >> 4, j = tid & 15;
    const int strip = j >> 2, joff = j & 3;
    const size_t xoff = (size_t)(16 * g + row) * 1024 + strip * 256 + q * 64 + joff * 16;
    const int xdst = row * 256 + strip * 64 + joff * 16;   // ushort idx in xl buffer
    {
        const unsigned short* src = xp + xoff;
        *(short8*)&xl0[xdst]     = *(const short8*)src;
        *(short8*)&xl0[xdst + 8] = *(const short8*)(src + 8);
    }
    __syncthreads();

    float c[4] = {0.f, 0.f, 0.f, 0.f};

    for (int t = 0; t < SEQ; ++t) {
        const int cur = t & 1;
        unsigned short* hbc = cur ? hb1 : hb0;   // h(t-1)
        unsigned short* hbn = cur ? hb0 : hb1;   // h(t) dest
        const unsigned short* xlc = cur ? xl1 : xl0;
        unsigned short* xln = cur ? xl0 : xl1;

        // prefetch next xp tile into regs (written to LDS at step end)
        short8 sv0, sv1;
        const bool do_stage = (t + 1 < SEQ);
        if (do_stage) {
            const unsigned short* src = xp + (size_t)(t + 1) * 131072 + xoff;
            sv0 = *(const short8*)src;
            sv1 = *(const short8*)(src + 8);
        }

        // prefetch-issue 3 partners' tagged words (4 each)
        unsigned int pw[3][4];
        const unsigned int* psrc[3];
        if (t > 0) {
            unsigned int* base = hxw + ((size_t)((cur ^ 1) * 8 + g) * 4) * 1024;
            #pragma unroll
            for (int d = 0; d < 3; ++d) {
                const int pqq = (q + 1 + d) & 3;
                psrc[d] = base + pqq * 1024 + row * 64 + j * 4;
                #pragma unroll
                for (int k = 0; k < 4; ++k)
                    pw[d][k] = __hip_atomic_load(psrc[d] + k, __ATOMIC_RELAXED, __HIP_MEMORY_SCOPE_AGENT);
            }
        }

        // own K-slices (units q*64..+64 -> slices 2q, 2q+1): no partner data needed
        f4 acc[4] = {};
        #pragma unroll
        for (int s = 0; s < 8; ++s) {
            if ((s >> 1) != q) continue;      // block-uniform guard, Br index static
            short8 av = *(const short8*)&hbc[ln * 264 + s * 32 + hi * 8];
            #pragma unroll
            for (int gq = 0; gq < 4; ++gq)
                acc[gq] = __builtin_amdgcn_mfma_f32_16x16x32_bf16(av, Br[s][gq], acc[gq], 0, 0, 0);
        }

        // wait for 3 partners' h(t-1), copy into hbc partner regions
        if (t > 0) {
            const unsigned int tag = (unsigned int)t;
            for (;;) {
                unsigned int bad = 0;
                #pragma unroll
                for (int d = 0; d < 3; ++d)
                    #pragma unroll
                    for (int k = 0; k < 4; ++k)
                        bad |= (pw[d][k] ^ tag);
                if ((bad & 0xffffu) == 0u) break;
                #pragma unroll
                for (int d = 0; d < 3; ++d)
                    #pragma unroll
                    for (int k = 0; k < 4; ++k)
                        pw[d][k] = __hip_atomic_load(psrc[d] + k, __ATOMIC_RELAXED, __HIP_MEMORY_SCOPE_AGENT);
            }
            #pragma unroll
            for (int d = 0; d < 3; ++d) {
                const int pqq = (q + 1 + d) & 3;
                unsigned long long packed = (unsigned long long)(pw[d][0] >> 16)
                    | ((unsigned long long)(pw[d][1] >> 16) << 16)
                    | ((unsigned long long)(pw[d][2] >> 16) << 32)
                    | ((unsigned long long)(pw[d][3] >> 16) << 48);
                *(unsigned long long*)&hbc[row * 264 + pqq * 64 + j * 4] = packed;
            }
        }
        __syncthreads();

        // partner K-slices
        #pragma unroll
        for (int s = 0; s < 8; ++s) {
            if ((s >> 1) == q) continue;
            short8 av = *(const short8*)&hbc[ln * 264 + s * 32 + hi * 8];
            #pragma unroll
            for (int gq = 0; gq < 4; ++gq)
                acc[gq] = __builtin_amdgcn_mfma_f32_16x16x32_bf16(av, Br[s][gq], acc[gq], 0, 0, 0);
        }

        // gates: lane owns 4 cells (rows 4hi+r, unit uin); xp from LDS
        unsigned int* pdst = hxw + ((size_t)(cur * 8 + g) * 4 + q) * 1024 + (4 * hi) * 64 + uin;
        const unsigned int tagn = (unsigned int)(t + 1);
        #pragma unroll
        for (int r = 0; r < 4; ++r) {
            const int xrb = (4 * hi + r) * 256 + uin;
            float vf = acc[0][r] + b2f(xlc[xrb]);
            float vi = acc[1][r] + b2f(xlc[xrb + 64]);
            float vc = acc[2][r] + b2f(xlc[xrb + 128]);
            float vo = acc[3][r] + b2f(xlc[xrb + 192]);
            float ea = __expf(-vf);
            float ei = __expf(-vi);
            float eb = __expf(-2.0f * vc);
            float eo = __expf(-vo);
            float rf = __builtin_amdgcn_rcpf(1.0f + ea);
            float it = (1.0f - eb) * __builtin_amdgcn_rcpf((1.0f + ei) * (1.0f + eb));
            float cn = fmaf(rf, c[r], it);
            c[r] = cn;
            float ed = __expf(-2.0f * cn);
            float h = (1.0f - ed) * __builtin_amdgcn_rcpf((1.0f + eo) * (1.0f + ed));
            unsigned short hb16 = f2b(h);
            hbn[(4 * hi + r) * 264 + ugl] = hb16;
            __hip_atomic_store(pdst + r * 64, ((unsigned int)hb16 << 16) | tagn,
                               __ATOMIC_RELAXED, __HIP_MEMORY_SCOPE_AGENT);
        }
        // write next xp tile to LDS (buffer no longer read this step)
        if (do_stage) {
            *(short8*)&xln[xdst]     = sv0;
            *(short8*)&xln[xdst + 8] = sv1;
        }
        __syncthreads();
    }

    // epilogue: partial FC over own 64 units (final h in hb0), atomicAdd (4 addends)
    if (tid < 32) {
        const int r = tid >> 1, o = tid & 1;
        float s = (q == 0) ? fc_b[o] : 0.0f;
        const unsigned short* hrow = hb0 + r * 264 + q * 64;
        for (int jj = 0; jj < 64; ++jj)
            s += b2f(hrow[jj]) * fc_w[o * HID + q * 64 + jj];
        atomicAdd(&out[(16 * g + r) * 2 + o], s);
    }
}

extern "C" void kernel_launch(void* const* d_in, const int* in_sizes, int n_in,
                              void* d_out, int out_size, void* d_ws, size_t ws_size,
                              hipStream_t stream) {
    const int*   tokens = (const int*)  d_in[0];
    const float* emb    = (const float*)d_in[1];
    const float* W_x    = (const float*)d_in[2];
    const float* b_x    = (const float*)d_in[3];
    const float* U_h    = (const float*)d_in[4];
    const float* b_u    = (const float*)d_in[5];
    const float* b_g    = (const float*)d_in[6];
    const float* fc_w   = (const float*)d_in[7];
    const float* fc_b   = (const float*)d_in[8];
    float* out = (float*)d_out;

    char* ws = (char*)d_ws;
    unsigned short* w_xb  = (unsigned short*)(ws);                 // 512 KB
    unsigned short* u_hb  = (unsigned short*)(ws + 524288);        // 512 KB
    float*          bias  = (float*)(ws + 1048576);                // 4 KB
    unsigned int*   hxw   = (unsigned int*)(ws + 1052672);         // 256 KB [2][8][4][16][64] u32
    unsigned short* xp    = (unsigned short*)(ws + 1314816);       // 128 MB bf16 [S][B][4H]

    prep_kernel<<<1024, 256, 0, stream>>>(W_x, U_h, b_x, b_u, b_g, w_xb, u_hb, bias,
                                          hxw, out);
    xp_gemm<<<1024, 256, 0, stream>>>(tokens, emb, w_xb, bias, xp);

    lstm_recur<<<32, 256, 0, stream>>>(xp, u_hb, fc_w, fc_b, hxw, out);
}

// Round 12
// 1036.782 us; speedup vs baseline: 1.5116x; 1.5116x over previous
//
#include <hip/hip_runtime.h>

typedef short short8 __attribute__((ext_vector_type(8)));
typedef float f4 __attribute__((ext_vector_type(4)));

#define BATCH 128
#define SEQ   512
#define EMB   256
#define HID   256
#define G4    1024   // 4*HID

static __device__ __forceinline__ unsigned short f2b(float f) {
    union { float f; unsigned int u; } v; v.f = f;
    unsigned int u = v.u;
    return (unsigned short)((u + 0x7FFFu + ((u >> 16) & 1u)) >> 16);  // RNE
}
static __device__ __forceinline__ float b2f(unsigned short s) {
    union { unsigned int u; float f; } v; v.u = ((unsigned int)s) << 16;
    return v.f;
}

// ---------------- Kernel 0: convert weights, fold biases, zero sync state -------
__global__ void prep_kernel(const float* __restrict__ W_x, const float* __restrict__ U_h,
                            const float* __restrict__ b_x, const float* __restrict__ b_u,
                            const float* __restrict__ b_g,
                            unsigned short* __restrict__ w_xb, unsigned short* __restrict__ u_hb,
                            float* __restrict__ bias,
                            unsigned int* __restrict__ hx32, float* __restrict__ out) {
    int i = blockIdx.x * blockDim.x + threadIdx.x;
    if (i < G4 * EMB) w_xb[i] = f2b(W_x[i]);
    if (i < G4 * HID) u_hb[i] = f2b(U_h[i]);
    if (i < G4) bias[i] = b_x[i] + b_u[i] + b_g[i];
    if (i < 65536) hx32[i] = 0;      // tag=0 everywhere (re-zeroed EVERY launch)
    if (i < 256) out[i] = 0.0f;      // out is atomicAdd-accumulated
}

// ---------------- Kernel 1: xp[s][b][g] = emb[tokens[b,s]] @ W_x^T + bias --------
__global__ __launch_bounds__(256) void xp_gemm(
    const int* __restrict__ tokens, const float* __restrict__ emb,
    const unsigned short* __restrict__ w_xb, const float* __restrict__ bias,
    unsigned short* __restrict__ xp)
{
    __shared__ unsigned short As[64][264];   // A tile
    __shared__ unsigned short Bs[64][264];   // staged B slice
    __shared__ unsigned short Xs[64][72];    // store-transpose bounce
    const int m0 = blockIdx.x * 64;
    const int b  = m0 >> 9;          // m0 / SEQ
    const int s0 = m0 & 511;         // m0 % SEQ
    const int tid = threadIdx.x;
    const int cS = tid >> 2, qS = (tid & 3) * 64;   // staging map (A and B)
    {
        const int tok = tokens[m0 + cS];
        const float* src = emb + (long)tok * EMB + qS;
        #pragma unroll
        for (int i = 0; i < 8; ++i) {
            float4 v0 = ((const float4*)src)[2 * i];
            float4 v1 = ((const float4*)src)[2 * i + 1];
            short8 pk;
            pk[0] = (short)f2b(v0.x); pk[1] = (short)f2b(v0.y);
            pk[2] = (short)f2b(v0.z); pk[3] = (short)f2b(v0.w);
            pk[4] = (short)f2b(v1.x); pk[5] = (short)f2b(v1.y);
            pk[6] = (short)f2b(v1.z); pk[7] = (short)f2b(v1.w);
            *(short8*)&As[cS][qS + i * 8] = pk;
        }
    }
    __syncthreads();
    const int w = tid >> 6, l = tid & 63;
    const int ln = l & 15, hi = l >> 4;
    short8 a[8];
    #pragma unroll
    for (int kk = 0; kk < 8; ++kk)
        a[kk] = *(const short8*)&As[16 * w + ln][kk * 32 + hi * 8];

    const int rl = tid >> 2;            // global-store row (own wave's rows)
    const int cl = (tid & 3) * 16;      // global-store col offset in 64-tile

    for (int n0 = 0; n0 < G4; n0 += 64) {
        {
            const unsigned short* src = &w_xb[(size_t)(n0 + cS) * EMB + qS];
            #pragma unroll
            for (int i = 0; i < 8; ++i)
                *(short8*)&Bs[cS][qS + i * 8] = *(const short8*)&src[i * 8];
        }
        __syncthreads();
        f4 acc[4] = {};
        #pragma unroll
        for (int kk = 0; kk < 8; ++kk) {
            #pragma unroll
            for (int nn = 0; nn < 4; ++nn) {
                short8 bfr = *(const short8*)&Bs[nn * 16 + ln][kk * 32 + hi * 8];
                acc[nn] = __builtin_amdgcn_mfma_f32_16x16x32_bf16(a[kk], bfr, acc[nn], 0, 0, 0);
            }
        }
        #pragma unroll
        for (int nn = 0; nn < 4; ++nn) {
            const float bs = bias[n0 + nn * 16 + ln];
            #pragma unroll
            for (int r = 0; r < 4; ++r)
                Xs[16 * w + 4 * hi + r][nn * 16 + ln] = f2b(acc[nn][r] + bs);
        }
        size_t off = ((size_t)(s0 + rl) * BATCH + b) * G4 + n0 + cl;
        *(short8*)&xp[off]     = *(const short8*)&Xs[rl][cl];
        *(short8*)&xp[off + 8] = *(const short8*)&Xs[rl][cl + 8];
        __syncthreads();
    }
}

// ---------------- Kernel 2: LSTM, 32 blocks = 8 groups x 4 quarters, 512 thr ----
// Block (g=bid&7, Q=bid>>3): batch rows 16g..+16, units Q*64..+64, all 4 gates.
// Wave w = 4*wp + wu: gate pair {2wp, 2wp+1} x units [wu*16, wu*16+16).
// B-quarter fully in regs: Br[8 slices][2 gates] = 16 frags = 64 VGPRs/thread.
// Gate bounce: acc -> gacc LDS ([4 gq][64 u][17-padded rows] f32), cells
// recombined 2/thread (rows w, w+8, unit l). Exchange = r10 tagged-word
// protocol, 3 partners, poll 6 words/thread. Own slices (2Q,2Q+1) before wait.
__global__ void __launch_bounds__(512, 2)
lstm_recur(const unsigned short* __restrict__ xp,
           const unsigned short* __restrict__ u_hb,
           const float* __restrict__ fc_w, const float* __restrict__ fc_b,
           unsigned int* __restrict__ hxw, float* __restrict__ out)
{
    __shared__ unsigned short hb0[16 * 264];   // h, parity 0 (264-us rows)
    __shared__ unsigned short hb1[16 * 264];   // h, parity 1
    __shared__ unsigned short xl0[16 * 256];   // xp tile, parity 0
    __shared__ unsigned short xl1[16 * 256];   // xp tile, parity 1
    __shared__ float gacc[4352];               // [gq*64+u][17] row-padded bounce
    const int tid = threadIdx.x;
    const int w = tid >> 6, l = tid & 63;
    const int ln = l & 15, hi = l >> 4;
    const int bid = blockIdx.x;
    const int g = bid & 7, Q = bid >> 3;
    const int wu = w & 3, wp = w >> 2;
    const int u16 = wu * 16 + ln;              // acc-col unit within quarter

    // B regs: 8 K-slices x 2 gates = 16 frags = 64 VGPRs
    short8 Br[8][2];
    #pragma unroll
    for (int s = 0; s < 8; ++s)
        #pragma unroll
        for (int p = 0; p < 2; ++p) {
            const int col = (2 * wp + p) * 256 + Q * 64 + u16;
            Br[s][p] = *(const short8*)&u_hb[(size_t)col * HID + s * 32 + hi * 8];
        }

    // zero both h buffers (8448 B each)
    for (int i = tid; i < 2112; i += 512) { ((unsigned*)hb0)[i] = 0; ((unsigned*)hb1)[i] = 0; }

    // xp staging: thread -> (row=tid>>5, 8-us chunk j8)
    const int xrow = tid >> 5, j8 = (tid & 31) * 8;
    const size_t xoff = (size_t)(16 * g + xrow) * 1024 + (j8 >> 6) * 256 + Q * 64 + (j8 & 63);
    const int xdst = xrow * 256 + j8;
    *(short8*)&xl0[xdst] = *(const short8*)(xp + xoff);
    __syncthreads();

    float c0 = 0.0f, c1 = 0.0f;   // cell states: (row w, unit l), (row w+8, unit l)

    for (int t = 0; t < SEQ; ++t) {
        const int cur = t & 1;
        unsigned short* hbc = cur ? hb1 : hb0;       // h(t-1)
        unsigned short* hbn = cur ? hb0 : hb1;       // h(t) dest
        const unsigned short* xlc = cur ? xl1 : xl0;
        unsigned short* xln = cur ? xl0 : xl1;

        // prefetch next xp chunk (consumed at step end)
        short8 sv;
        const bool do_stage = (t + 1 < SEQ);
        if (do_stage) sv = *(const short8*)(xp + (size_t)(t + 1) * 131072 + xoff);

        // issue 3 partners' tagged words (2 each)
        unsigned int pw[3][2];
        const unsigned int* ps[3];
        if (t > 0) {
            unsigned int* base = hxw + ((size_t)((cur ^ 1) * 8 + g)) * 4096;
            #pragma unroll
            for (int d = 0; d < 3; ++d) {
                const int pqq = (Q + 1 + d) & 3;
                ps[d] = base + pqq * 1024 + tid * 2;
                pw[d][0] = __hip_atomic_load(ps[d] + 0, __ATOMIC_RELAXED, __HIP_MEMORY_SCOPE_AGENT);
                pw[d][1] = __hip_atomic_load(ps[d] + 1, __ATOMIC_RELAXED, __HIP_MEMORY_SCOPE_AGENT);
            }
        }

        // own K-slices (2Q, 2Q+1): read only own units region of hbc
        f4 acc[2] = {};
        #pragma unroll
        for (int s = 0; s < 8; ++s) {
            if ((s >> 1) == Q) {                  // block-uniform, Br index static
                short8 av = *(const short8*)&hbc[ln * 264 + s * 32 + hi * 8];
                #pragma unroll
                for (int p = 0; p < 2; ++p)
                    acc[p] = __builtin_amdgcn_mfma_f32_16x16x32_bf16(av, Br[s][p], acc[p], 0, 0, 0);
            }
        }

        // wait for 3 partners' h(t-1); copy in (1 packed u32 per partner)
        if (t > 0) {
            const unsigned int tag = (unsigned int)t;
            for (;;) {
                unsigned int bad = 0;
                #pragma unroll
                for (int d = 0; d < 3; ++d)
                    bad |= (pw[d][0] ^ tag) | (pw[d][1] ^ tag);
                if ((bad & 0xffffu) == 0u) break;
                #pragma unroll
                for (int d = 0; d < 3; ++d) {
                    pw[d][0] = __hip_atomic_load(ps[d] + 0, __ATOMIC_RELAXED, __HIP_MEMORY_SCOPE_AGENT);
                    pw[d][1] = __hip_atomic_load(ps[d] + 1, __ATOMIC_RELAXED, __HIP_MEMORY_SCOPE_AGENT);
                }
            }
            const int crow = tid >> 5, cu0 = (tid * 2) & 63;
            #pragma unroll
            for (int d = 0; d < 3; ++d) {
                const int pqq = (Q + 1 + d) & 3;
                unsigned int pk = (pw[d][0] >> 16) | ((pw[d][1] >> 16) << 16);
                *(unsigned int*)&hbc[crow * 264 + pqq * 64 + cu0] = pk;
            }
        }
        __syncthreads();

        // partner K-slices (6 of 8)
        #pragma unroll
        for (int s = 0; s < 8; ++s) {
            if ((s >> 1) != Q) {
                short8 av = *(const short8*)&hbc[ln * 264 + s * 32 + hi * 8];
                #pragma unroll
                for (int p = 0; p < 2; ++p)
                    acc[p] = __builtin_amdgcn_mfma_f32_16x16x32_bf16(av, Br[s][p], acc[p], 0, 0, 0);
            }
        }

        // bounce acc to gacc: [gq*64+u][17] f32, row idx hi*4+r
        #pragma unroll
        for (int p = 0; p < 2; ++p) {
            const int gq = 2 * wp + p;
            const int gb = (gq * 64 + u16) * 17 + hi * 4;
            #pragma unroll
            for (int r = 0; r < 4; ++r)
                gacc[gb + r] = acc[p][r];
        }
        __syncthreads();

        // gates: 2 cells/thread (rows w, w+8; unit l); xp from LDS
        unsigned int* pub = hxw + ((size_t)(cur * 8 + g) * 4 + Q) * 1024;
        const unsigned int tagn = (unsigned int)(t + 1);
        #pragma unroll
        for (int cell = 0; cell < 2; ++cell) {
            const int crow = w + cell * 8;
            float vf = gacc[(0 * 64 + l) * 17 + crow] + b2f(xlc[crow * 256 + l]);
            float vi = gacc[(1 * 64 + l) * 17 + crow] + b2f(xlc[crow * 256 + 64 + l]);
            float vc = gacc[(2 * 64 + l) * 17 + crow] + b2f(xlc[crow * 256 + 128 + l]);
            float vo = gacc[(3 * 64 + l) * 17 + crow] + b2f(xlc[crow * 256 + 192 + l]);
            float ea = __expf(-vf);
            float ei = __expf(-vi);
            float eb = __expf(-2.0f * vc);
            float eo = __expf(-vo);
            float rf = __builtin_amdgcn_rcpf(1.0f + ea);
            float it = (1.0f - eb) * __builtin_amdgcn_rcpf((1.0f + ei) * (1.0f + eb));
            float cc = cell ? c1 : c0;
            float cn = fmaf(rf, cc, it);
            if (cell) c1 = cn; else c0 = cn;
            float ed = __expf(-2.0f * cn);
            float h = (1.0f - ed) * __builtin_amdgcn_rcpf((1.0f + eo) * (1.0f + ed));
            unsigned short hb16 = f2b(h);
            hbn[crow * 264 + Q * 64 + l] = hb16;
            __hip_atomic_store(pub + crow * 64 + l, ((unsigned int)hb16 << 16) | tagn,
                               __ATOMIC_RELAXED, __HIP_MEMORY_SCOPE_AGENT);
        }
        // stage next xp tile (its buffer is not read this step)
        if (do_stage) *(short8*)&xln[xdst] = sv;
        __syncthreads();
    }

    // epilogue: partial FC over own 64 units (final h in hb0), atomicAdd (4 addends)
    if (tid < 32) {
        const int r = tid >> 1, o = tid & 1;
        float s = (Q == 0) ? fc_b[o] : 0.0f;
        const unsigned short* hrow = hb0 + r * 264 + Q * 64;
        for (int jj = 0; jj < 64; ++jj)
            s += b2f(hrow[jj]) * fc_w[o * HID + Q * 64 + jj];
        atomicAdd(&out[(16 * g + r) * 2 + o], s);
    }
}

extern "C" void kernel_launch(void* const* d_in, const int* in_sizes, int n_in,
                              void* d_out, int out_size, void* d_ws, size_t ws_size,
                              hipStream_t stream) {
    const int*   tokens = (const int*)  d_in[0];
    const float* emb    = (const float*)d_in[1];
    const float* W_x    = (const float*)d_in[2];
    const float* b_x    = (const float*)d_in[3];
    const float* U_h    = (const float*)d_in[4];
    const float* b_u    = (const float*)d_in[5];
    const float* b_g    = (const float*)d_in[6];
    const float* fc_w   = (const float*)d_in[7];
    const float* fc_b   = (const float*)d_in[8];
    float* out = (float*)d_out;

    char* ws = (char*)d_ws;
    unsigned short* w_xb  = (unsigned short*)(ws);                 // 512 KB
    unsigned short* u_hb  = (unsigned short*)(ws + 524288);        // 512 KB
    float*          bias  = (float*)(ws + 1048576);                // 4 KB
    unsigned int*   hxw   = (unsigned int*)(ws + 1052672);         // 256 KB [2][8][4][16][64] u32
    unsigned short* xp    = (unsigned short*)(ws + 1314816);       // 128 MB bf16 [S][B][4H]

    prep_kernel<<<1024, 256, 0, stream>>>(W_x, U_h, b_x, b_u, b_g, w_xb, u_hb, bias,
                                          hxw, out);
    xp_gemm<<<1024, 256, 0, stream>>>(tokens, emb, w_xb, bias, xp);

    lstm_recur<<<32, 512, 0, stream>>>(xp, u_hb, fc_w, fc_b, hxw, out);
}

// Round 13
// 859.270 us; speedup vs baseline: 1.8238x; 1.2066x over previous
//
#include <hip/hip_runtime.h>

typedef short short8 __attribute__((ext_vector_type(8)));
typedef float f4 __attribute__((ext_vector_type(4)));

#define BATCH 128
#define SEQ   512
#define EMB   256
#define HID   256
#define G4    1024   // 4*HID

static __device__ __forceinline__ unsigned short f2b(float f) {
    union { float f; unsigned int u; } v; v.f = f;
    unsigned int u = v.u;
    return (unsigned short)((u + 0x7FFFu + ((u >> 16) & 1u)) >> 16);  // RNE
}
static __device__ __forceinline__ float b2f(unsigned short s) {
    union { unsigned int u; float f; } v; v.u = ((unsigned int)s) << 16;
    return v.f;
}

// ---------------- Kernel 0: convert weights, fold biases, zero sync state -------
__global__ void prep_kernel(const float* __restrict__ W_x, const float* __restrict__ U_h,
                            const float* __restrict__ b_x, const float* __restrict__ b_u,
                            const float* __restrict__ b_g,
                            unsigned short* __restrict__ w_xb, unsigned short* __restrict__ u_hb,
                            float* __restrict__ bias,
                            unsigned int* __restrict__ hx32, float* __restrict__ out) {
    int i = blockIdx.x * blockDim.x + threadIdx.x;
    if (i < G4 * EMB) w_xb[i] = f2b(W_x[i]);
    if (i < G4 * HID) u_hb[i] = f2b(U_h[i]);
    if (i < G4) bias[i] = b_x[i] + b_u[i] + b_g[i];
    if (i < 65536) hx32[i] = 0;      // tag=0 everywhere (re-zeroed EVERY launch)
    if (i < 256) out[i] = 0.0f;      // out is atomicAdd-accumulated
}

// ---------------- Kernel 1: xp[s][b][g] = emb[tokens[b,s]] @ W_x^T + bias --------
__global__ __launch_bounds__(256) void xp_gemm(
    const int* __restrict__ tokens, const float* __restrict__ emb,
    const unsigned short* __restrict__ w_xb, const float* __restrict__ bias,
    unsigned short* __restrict__ xp)
{
    __shared__ unsigned short As[64][264];   // A tile
    __shared__ unsigned short Bs[64][264];   // staged B slice
    __shared__ unsigned short Xs[64][72];    // store-transpose bounce
    const int m0 = blockIdx.x * 64;
    const int b  = m0 >> 9;          // m0 / SEQ
    const int s0 = m0 & 511;         // m0 % SEQ
    const int tid = threadIdx.x;
    const int cS = tid >> 2, qS = (tid & 3) * 64;   // staging map (A and B)
    {
        const int tok = tokens[m0 + cS];
        const float* src = emb + (long)tok * EMB + qS;
        #pragma unroll
        for (int i = 0; i < 8; ++i) {
            float4 v0 = ((const float4*)src)[2 * i];
            float4 v1 = ((const float4*)src)[2 * i + 1];
            short8 pk;
            pk[0] = (short)f2b(v0.x); pk[1] = (short)f2b(v0.y);
            pk[2] = (short)f2b(v0.z); pk[3] = (short)f2b(v0.w);
            pk[4] = (short)f2b(v1.x); pk[5] = (short)f2b(v1.y);
            pk[6] = (short)f2b(v1.z); pk[7] = (short)f2b(v1.w);
            *(short8*)&As[cS][qS + i * 8] = pk;
        }
    }
    __syncthreads();
    const int w = tid >> 6, l = tid & 63;
    const int ln = l & 15, hi = l >> 4;
    short8 a[8];
    #pragma unroll
    for (int kk = 0; kk < 8; ++kk)
        a[kk] = *(const short8*)&As[16 * w + ln][kk * 32 + hi * 8];

    const int rl = tid >> 2;            // global-store row (own wave's rows)
    const int cl = (tid & 3) * 16;      // global-store col offset in 64-tile

    for (int n0 = 0; n0 < G4; n0 += 64) {
        {
            const unsigned short* src = &w_xb[(size_t)(n0 + cS) * EMB + qS];
            #pragma unroll
            for (int i = 0; i < 8; ++i)
                *(short8*)&Bs[cS][qS + i * 8] = *(const short8*)&src[i * 8];
        }
        __syncthreads();
        f4 acc[4] = {};
        #pragma unroll
        for (int kk = 0; kk < 8; ++kk) {
            #pragma unroll
            for (int nn = 0; nn < 4; ++nn) {
                short8 bfr = *(const short8*)&Bs[nn * 16 + ln][kk * 32 + hi * 8];
                acc[nn] = __builtin_amdgcn_mfma_f32_16x16x32_bf16(a[kk], bfr, acc[nn], 0, 0, 0);
            }
        }
        #pragma unroll
        for (int nn = 0; nn < 4; ++nn) {
            const float bs = bias[n0 + nn * 16 + ln];
            #pragma unroll
            for (int r = 0; r < 4; ++r)
                Xs[16 * w + 4 * hi + r][nn * 16 + ln] = f2b(acc[nn][r] + bs);
        }
        size_t off = ((size_t)(s0 + rl) * BATCH + b) * G4 + n0 + cl;
        *(short8*)&xp[off]     = *(const short8*)&Xs[rl][cl];
        *(short8*)&xp[off + 8] = *(const short8*)&Xs[rl][cl + 8];
        __syncthreads();
    }
}

// ---------------- Kernel 2: LSTM, 32 blocks = 8 groups x 4 quarters, 512 thr ----
// SWAPPED-OPERAND MFMA: C = U_reord(A) x h^T(B). U_h cols reordered unit-major/
// gate-minor (gu = u*4+gate) => acc[m][r] = gate r of cell (unit mt*4+hi, batch ln):
// all 4 gates in one lane, no compaction/bounce. A-frags Br[8][2] = 64 regs (AGPR).
// B-frags: h^T slice-layout LDS, frag read = &hsl[s*512 + l*8] (2-way alias, free).
// Exchange: r10 tagged-word protocol, 3 partners, 1 u64 poll each.
__global__ void __launch_bounds__(512, 2)
lstm_recur(const unsigned short* __restrict__ xp,
           const unsigned short* __restrict__ u_hb,
           const float* __restrict__ fc_w, const float* __restrict__ fc_b,
           unsigned int* __restrict__ hxw, float* __restrict__ out)
{
    __shared__ unsigned short hsl0[4096];      // h slice-layout, parity 0: [8 s][512]
    __shared__ unsigned short hsl1[4096];      // parity 1
    __shared__ unsigned short xl0[16 * 264];   // xp tile [batch][gate*64+unit], 264-pad
    __shared__ unsigned short xl1[16 * 264];
    const int tid = threadIdx.x;
    const int w = tid >> 6, l = tid & 63;
    const int ln = l & 15, hi = l >> 4;
    const int bid = blockIdx.x;
    const int g = bid & 7, Q = bid >> 3;

    // A-frags: Br[s][m], row gu = mt*16+ln -> col_gm = (ln&3)*256 + Q*64 + mt*4 + (ln>>2)
    short8 Br[8][2];
    #pragma unroll
    for (int s = 0; s < 8; ++s)
        #pragma unroll
        for (int m = 0; m < 2; ++m) {
            const int mt = w * 2 + m;
            const int col = (ln & 3) * 256 + Q * 64 + mt * 4 + (ln >> 2);
            Br[s][m] = *(const short8*)&u_hb[(size_t)col * HID + s * 32 + hi * 8];
        }

    // zero both h slice buffers (h(-1) = 0)
    for (int i = tid; i < 2048; i += 512) { ((unsigned*)hsl0)[i] = 0; ((unsigned*)hsl1)[i] = 0; }

    // xp staging: thread -> (batch row xrow, 8-us chunk of gate strip)
    const int xrow = tid >> 5, j8 = (tid & 31) * 8;
    const size_t xoff = (size_t)(16 * g + xrow) * 1024 + (j8 >> 6) * 256 + Q * 64 + (j8 & 63);
    const int xdst = xrow * 264 + (j8 >> 6) * 64 + (j8 & 63);
    *(short8*)&xl0[xdst] = *(const short8*)(xp + xoff);
    __syncthreads();

    float c0 = 0.0f, c1 = 0.0f;   // cell states for m=0,1 (unit (2w+m)*4+hi, batch ln)

    for (int t = 0; t < SEQ; ++t) {
        const int cur = t & 1;
        unsigned short* hslc = cur ? hsl1 : hsl0;    // h(t-1), B-frag layout
        unsigned short* hsln = cur ? hsl0 : hsl1;    // h(t) dest
        const unsigned short* xlc = cur ? xl1 : xl0;
        unsigned short* xln = cur ? xl0 : xl1;

        // prefetch next xp chunk (LDS-written at step end)
        short8 sv;
        const bool do_stage = (t + 1 < SEQ);
        if (do_stage) sv = *(const short8*)(xp + (size_t)(t + 1) * 131072 + xoff);

        // issue 3 partners' tagged words (1 u64 each: words 2tid, 2tid+1)
        unsigned long long pw[3];
        const unsigned long long* ps[3];
        if (t > 0) {
            unsigned int* base = hxw + ((size_t)((cur ^ 1) * 8 + g)) * 4096;
            #pragma unroll
            for (int d = 0; d < 3; ++d) {
                const int pq = (Q + 1 + d) & 3;
                ps[d] = (const unsigned long long*)(base + pq * 1024 + 2 * tid);
                pw[d] = __hip_atomic_load(ps[d], __ATOMIC_RELAXED, __HIP_MEMORY_SCOPE_AGENT);
            }
        }

        // own K-slices (2Q, 2Q+1): own-quarter h written by us last step
        f4 acc[2] = {};
        #pragma unroll
        for (int s = 0; s < 8; ++s) {
            if ((s >> 1) == Q) {
                short8 hf = *(const short8*)&hslc[s * 512 + l * 8];
                acc[0] = __builtin_amdgcn_mfma_f32_16x16x32_bf16(Br[s][0], hf, acc[0], 0, 0, 0);
                acc[1] = __builtin_amdgcn_mfma_f32_16x16x32_bf16(Br[s][1], hf, acc[1], 0, 0, 0);
            }
        }

        // wait for 3 partners; scatter their h into slice-layout
        if (t > 0) {
            const unsigned long long tt = (unsigned long long)(unsigned)t
                                        | ((unsigned long long)(unsigned)t << 32);
            for (;;) {
                unsigned long long bad = 0;
                #pragma unroll
                for (int d = 0; d < 3; ++d) bad |= (pw[d] ^ tt);
                if ((bad & 0x0000ffff0000ffffULL) == 0ULL) break;
                #pragma unroll
                for (int d = 0; d < 3; ++d)
                    pw[d] = __hip_atomic_load(ps[d], __ATOMIC_RELAXED, __HIP_MEMORY_SCOPE_AGENT);
            }
            #pragma unroll
            for (int d = 0; d < 3; ++d) {
                const int pq = (Q + 1 + d) & 3;
                #pragma unroll
                for (int e = 0; e < 2; ++e) {
                    const unsigned int word = (unsigned int)(pw[d] >> (32 * e));
                    const int wi = 2 * tid + e;
                    const int b = wi & 15, up = wi >> 4;
                    const int ug = pq * 64 + up;
                    const int ss = ug >> 5, k = ug & 31;
                    hslc[ss * 512 + ((k >> 3) * 16 + b) * 8 + (k & 7)] = (unsigned short)(word >> 16);
                }
            }
        }
        __syncthreads();

        // partner K-slices (6 of 8)
        #pragma unroll
        for (int s = 0; s < 8; ++s) {
            if ((s >> 1) != Q) {
                short8 hf = *(const short8*)&hslc[s * 512 + l * 8];
                acc[0] = __builtin_amdgcn_mfma_f32_16x16x32_bf16(Br[s][0], hf, acc[0], 0, 0, 0);
                acc[1] = __builtin_amdgcn_mfma_f32_16x16x32_bf16(Br[s][1], hf, acc[1], 0, 0, 0);
            }
        }

        // gates: acc[m][r] = gate r of (unit (2w+m)*4+hi, batch ln)
        unsigned int* pub = hxw + ((size_t)(cur * 8 + g) * 4 + Q) * 1024;
        const unsigned int tagn = (unsigned int)(t + 1);
        #pragma unroll
        for (int m = 0; m < 2; ++m) {
            const int uin = (w * 2 + m) * 4 + hi;
            const int xb = ln * 264 + uin;
            float vf = acc[m][0] + b2f(xlc[xb]);
            float vi = acc[m][1] + b2f(xlc[xb + 64]);
            float vc = acc[m][2] + b2f(xlc[xb + 128]);
            float vo = acc[m][3] + b2f(xlc[xb + 192]);
            float ea = __expf(-vf);
            float ei = __expf(-vi);
            float eb = __expf(-2.0f * vc);
            float eo = __expf(-vo);
            float rf = __builtin_amdgcn_rcpf(1.0f + ea);
            float it = (1.0f - eb) * __builtin_amdgcn_rcpf((1.0f + ei) * (1.0f + eb));
            float cc = m ? c1 : c0;
            float cn = fmaf(rf, cc, it);
            if (m) c1 = cn; else c0 = cn;
            float ed = __expf(-2.0f * cn);
            float h = (1.0f - ed) * __builtin_amdgcn_rcpf((1.0f + eo) * (1.0f + ed));
            unsigned short hb16 = f2b(h);
            const int ug = Q * 64 + uin;
            const int ss = ug >> 5, k = ug & 31;
            hsln[ss * 512 + ((k >> 3) * 16 + ln) * 8 + (k & 7)] = hb16;
            __hip_atomic_store(pub + uin * 16 + ln, ((unsigned int)hb16 << 16) | tagn,
                               __ATOMIC_RELAXED, __HIP_MEMORY_SCOPE_AGENT);
        }
        // stage next xp tile (buffer not read this step)
        if (do_stage) *(short8*)&xln[xdst] = sv;
        __syncthreads();
    }

    // epilogue: own 64 units of h(511) live in hsl0 (t=511 wrote parity 0)
    if (tid < 32) {
        const int r = tid >> 1, o = tid & 1;
        float acc_fc = (Q == 0) ? fc_b[o] : 0.0f;
        for (int jj = 0; jj < 64; ++jj) {
            const int ug = Q * 64 + jj;
            const int ss = ug >> 5, k = ug & 31;
            float h = b2f(hsl0[ss * 512 + ((k >> 3) * 16 + r) * 8 + (k & 7)]);
            acc_fc += h * fc_w[o * HID + ug];
        }
        atomicAdd(&out[(16 * g + r) * 2 + o], acc_fc);
    }
}

extern "C" void kernel_launch(void* const* d_in, const int* in_sizes, int n_in,
                              void* d_out, int out_size, void* d_ws, size_t ws_size,
                              hipStream_t stream) {
    const int*   tokens = (const int*)  d_in[0];
    const float* emb    = (const float*)d_in[1];
    const float* W_x    = (const float*)d_in[2];
    const float* b_x    = (const float*)d_in[3];
    const float* U_h    = (const float*)d_in[4];
    const float* b_u    = (const float*)d_in[5];
    const float* b_g    = (const float*)d_in[6];
    const float* fc_w   = (const float*)d_in[7];
    const float* fc_b   = (const float*)d_in[8];
    float* out = (float*)d_out;

    char* ws = (char*)d_ws;
    unsigned short* w_xb  = (unsigned short*)(ws);                 // 512 KB
    unsigned short* u_hb  = (unsigned short*)(ws + 524288);        // 512 KB
    float*          bias  = (float*)(ws + 1048576);                // 4 KB
    unsigned int*   hxw   = (unsigned int*)(ws + 1052672);         // 256 KB [2][8][4][64][16] u32
    unsigned short* xp    = (unsigned short*)(ws + 1314816);       // 128 MB bf16 [S][B][4H]

    prep_kernel<<<1024, 256, 0, stream>>>(W_x, U_h, b_x, b_u, b_g, w_xb, u_hb, bias,
                                          hxw, out);
    xp_gemm<<<1024, 256, 0, stream>>>(tokens, emb, w_xb, bias, xp);

    lstm_recur<<<32, 512, 0, stream>>>(xp, u_hb, fc_w, fc_b, hxw, out);
}

// Round 14
// 783.589 us; speedup vs baseline: 2.0000x; 1.0966x over previous
//
#include <hip/hip_runtime.h>

typedef short short8 __attribute__((ext_vector_type(8)));
typedef float f4 __attribute__((ext_vector_type(4)));

#define BATCH 128
#define SEQ   512
#define EMB   256
#define HID   256
#define G4    1024   // 4*HID

static __device__ __forceinline__ unsigned short f2b(float f) {
    union { float f; unsigned int u; } v; v.f = f;
    unsigned int u = v.u;
    return (unsigned short)((u + 0x7FFFu + ((u >> 16) & 1u)) >> 16);  // RNE
}
static __device__ __forceinline__ float b2f(unsigned short s) {
    union { unsigned int u; float f; } v; v.u = ((unsigned int)s) << 16;
    return v.f;
}

// ---------------- Kernel 0: convert weights, fold biases, zero sync state -------
__global__ void prep_kernel(const float* __restrict__ W_x, const float* __restrict__ U_h,
                            const float* __restrict__ b_x, const float* __restrict__ b_u,
                            const float* __restrict__ b_g,
                            unsigned short* __restrict__ w_xb, unsigned short* __restrict__ u_hb,
                            float* __restrict__ bias,
                            unsigned int* __restrict__ hx32, float* __restrict__ out) {
    int i = blockIdx.x * blockDim.x + threadIdx.x;
    if (i < G4 * EMB) w_xb[i] = f2b(W_x[i]);
    if (i < G4 * HID) u_hb[i] = f2b(U_h[i]);
    if (i < G4) bias[i] = b_x[i] + b_u[i] + b_g[i];
    if (i < 65536) hx32[i] = 0;      // tag=0 everywhere (re-zeroed EVERY launch)
    if (i < 256) out[i] = 0.0f;      // out is atomicAdd-accumulated
}

// ---------------- Kernel 1: xp[s][b][g] = emb[tokens[b,s]] @ W_x^T + bias --------
__global__ __launch_bounds__(256) void xp_gemm(
    const int* __restrict__ tokens, const float* __restrict__ emb,
    const unsigned short* __restrict__ w_xb, const float* __restrict__ bias,
    unsigned short* __restrict__ xp)
{
    __shared__ unsigned short As[64][264];   // A tile
    __shared__ unsigned short Bs[64][264];   // staged B slice
    __shared__ unsigned short Xs[64][72];    // store-transpose bounce
    const int m0 = blockIdx.x * 64;
    const int b  = m0 >> 9;          // m0 / SEQ
    const int s0 = m0 & 511;         // m0 % SEQ
    const int tid = threadIdx.x;
    const int cS = tid >> 2, qS = (tid & 3) * 64;   // staging map (A and B)
    {
        const int tok = tokens[m0 + cS];
        const float* src = emb + (long)tok * EMB + qS;
        #pragma unroll
        for (int i = 0; i < 8; ++i) {
            float4 v0 = ((const float4*)src)[2 * i];
            float4 v1 = ((const float4*)src)[2 * i + 1];
            short8 pk;
            pk[0] = (short)f2b(v0.x); pk[1] = (short)f2b(v0.y);
            pk[2] = (short)f2b(v0.z); pk[3] = (short)f2b(v0.w);
            pk[4] = (short)f2b(v1.x); pk[5] = (short)f2b(v1.y);
            pk[6] = (short)f2b(v1.z); pk[7] = (short)f2b(v1.w);
            *(short8*)&As[cS][qS + i * 8] = pk;
        }
    }
    __syncthreads();
    const int w = tid >> 6, l = tid & 63;
    const int ln = l & 15, hi = l >> 4;
    short8 a[8];
    #pragma unroll
    for (int kk = 0; kk < 8; ++kk)
        a[kk] = *(const short8*)&As[16 * w + ln][kk * 32 + hi * 8];

    const int rl = tid >> 2;            // global-store row (own wave's rows)
    const int cl = (tid & 3) * 16;      // global-store col offset in 64-tile

    for (int n0 = 0; n0 < G4; n0 += 64) {
        {
            const unsigned short* src = &w_xb[(size_t)(n0 + cS) * EMB + qS];
            #pragma unroll
            for (int i = 0; i < 8; ++i)
                *(short8*)&Bs[cS][qS + i * 8] = *(const short8*)&src[i * 8];
        }
        __syncthreads();
        f4 acc[4] = {};
        #pragma unroll
        for (int kk = 0; kk < 8; ++kk) {
            #pragma unroll
            for (int nn = 0; nn < 4; ++nn) {
                short8 bfr = *(const short8*)&Bs[nn * 16 + ln][kk * 32 + hi * 8];
                acc[nn] = __builtin_amdgcn_mfma_f32_16x16x32_bf16(a[kk], bfr, acc[nn], 0, 0, 0);
            }
        }
        #pragma unroll
        for (int nn = 0; nn < 4; ++nn) {
            const float bs = bias[n0 + nn * 16 + ln];
            #pragma unroll
            for (int r = 0; r < 4; ++r)
                Xs[16 * w + 4 * hi + r][nn * 16 + ln] = f2b(acc[nn][r] + bs);
        }
        size_t off = ((size_t)(s0 + rl) * BATCH + b) * G4 + n0 + cl;
        *(short8*)&xp[off]     = *(const short8*)&Xs[rl][cl];
        *(short8*)&xp[off + 8] = *(const short8*)&Xs[rl][cl + 8];
        __syncthreads();
    }
}

// ---------------- Kernel 2: LSTM, 32 blocks = 8 groups x 4 quarters, 512 thr ----
// r13 structure (swapped-operand MFMA, tagged-word exchange) + micro-opts:
// u64 publish (thread's 2 tagged words adjacent), hoisted loop-invariant offsets,
// rotated slice order (own=Br[0..1], no runtime guards), cvt_pk_bf16 packing.
// hxw word order: word idx = 2*tid + m within quarter; unit=8w+4m+hi, batch=ln.
__global__ void __launch_bounds__(512, 2)
lstm_recur(const unsigned short* __restrict__ xp,
           const unsigned short* __restrict__ u_hb,
           const float* __restrict__ fc_w, const float* __restrict__ fc_b,
           unsigned int* __restrict__ hxw, float* __restrict__ out)
{
    __shared__ unsigned short hsl0[4096];      // h slice-layout, parity 0: [8 s][512]
    __shared__ unsigned short hsl1[4096];      // parity 1
    __shared__ unsigned short xl0[16 * 264];   // xp tile [batch][gate*64+unit], 264-pad
    __shared__ unsigned short xl1[16 * 264];
    const int tid = threadIdx.x;
    const int w = tid >> 6, l = tid & 63;
    const int ln = l & 15, hi = l >> 4;
    const int bid = blockIdx.x;
    const int g = bid & 7, Q = bid >> 3;

    // A-frags in rotated slice order: Br[j] holds slice s=(2Q+j)&7. Own: j=0,1.
    short8 Br[8][2];
    int fo[8];                                   // frag LDS offsets (block-uniform)
    #pragma unroll
    for (int j = 0; j < 8; ++j) {
        const int s = (2 * Q + j) & 7;
        fo[j] = s * 512;
        #pragma unroll
        for (int m = 0; m < 2; ++m) {
            const int mt = w * 2 + m;
            const int col = (ln & 3) * 256 + Q * 64 + mt * 4 + (ln >> 2);
            Br[j][m] = *(const short8*)&u_hb[(size_t)col * HID + s * 32 + hi * 8];
        }
    }

    // zero both h slice buffers (h(-1) = 0)
    for (int i = tid; i < 2048; i += 512) { ((unsigned*)hsl0)[i] = 0; ((unsigned*)hsl1)[i] = 0; }

    // xp staging: thread -> (batch row xrow, 8-us chunk of gate strip)
    const int xrow = tid >> 5, j8 = (tid & 31) * 8;
    const size_t xoff = (size_t)(16 * g + xrow) * 1024 + (j8 >> 6) * 256 + Q * 64 + (j8 & 63);
    const int xdst = xrow * 264 + (j8 >> 6) * 64 + (j8 & 63);
    *(short8*)&xl0[xdst] = *(const short8*)(xp + xoff);
    __syncthreads();

    // ---- hoisted loop-invariant offsets ----
    // poll slot (u64 units) per read-parity: ((par*8+g)*4 + pq)*512 + tid
    const unsigned long long* hx64 = (const unsigned long long*)hxw;
    int po0[2], po1[2], po2[2], pub[2];
    #pragma unroll
    for (int par = 0; par < 2; ++par) {
        const int base = (par * 8 + g) * 2048 + tid;
        po0[par] = base + (((Q + 1) & 3) << 9);
        po1[par] = base + (((Q + 2) & 3) << 9);
        po2[par] = base + (((Q + 3) & 3) << 9);
        pub[par] = base + (Q << 9);
    }
    // scatter dests (ushort idx into hslc) for (partner d, word e)
    int sf[3][2];
    #pragma unroll
    for (int d = 0; d < 3; ++d)
        #pragma unroll
        for (int e = 0; e < 2; ++e) {
            const int pq = (Q + 1 + d) & 3;
            const int unit = 8 * w + 4 * e + hi;
            const int ug = pq * 64 + unit;
            const int ss = ug >> 5, k = ug & 31;
            sf[d][e] = ss * 512 + ((k >> 3) * 16 + ln) * 8 + (k & 7);
        }
    // own h-store dests + xp gate-read bases
    const int u0 = 8 * w + hi, u1 = u0 + 4;
    int ho[2], xb[2];
    #pragma unroll
    for (int m = 0; m < 2; ++m) {
        const int uin = m ? u1 : u0;
        const int ug = Q * 64 + uin;
        const int ss = ug >> 5, k = ug & 31;
        ho[m] = ss * 512 + ((k >> 3) * 16 + ln) * 8 + (k & 7);
        xb[m] = ln * 264 + uin;
    }
    const int fro = l * 8;     // frag read lane offset

    float c0 = 0.0f, c1 = 0.0f;

    for (int t = 0; t < SEQ; ++t) {
        const int cur = t & 1;
        unsigned short* hslc = cur ? hsl1 : hsl0;    // h(t-1), B-frag layout
        unsigned short* hsln = cur ? hsl0 : hsl1;    // h(t) dest
        const unsigned short* xlc = cur ? xl1 : xl0;
        unsigned short* xln = cur ? xl0 : xl1;

        // issue 3 partners' tagged u64s first (oldest in VMEM queue)
        unsigned long long pw0 = 0, pw1 = 0, pw2 = 0;
        const unsigned long long *ps0 = hx64, *ps1 = hx64, *ps2 = hx64;
        if (t > 0) {
            const int par = cur ^ 1;
            ps0 = hx64 + po0[par]; ps1 = hx64 + po1[par]; ps2 = hx64 + po2[par];
            pw0 = __hip_atomic_load(ps0, __ATOMIC_RELAXED, __HIP_MEMORY_SCOPE_AGENT);
            pw1 = __hip_atomic_load(ps1, __ATOMIC_RELAXED, __HIP_MEMORY_SCOPE_AGENT);
            pw2 = __hip_atomic_load(ps2, __ATOMIC_RELAXED, __HIP_MEMORY_SCOPE_AGENT);
        }
        // prefetch next xp chunk (LDS-written at step end)
        short8 sv;
        const bool do_stage = (t + 1 < SEQ);
        if (do_stage) sv = *(const short8*)(xp + (size_t)(t + 1) * 131072 + xoff);

        // own K-slices: Br[0], Br[1] (slices 2Q, 2Q+1; own-quarter h)
        f4 acc[2] = {};
        {
            short8 hf = *(const short8*)&hslc[fo[0] + fro];
            acc[0] = __builtin_amdgcn_mfma_f32_16x16x32_bf16(Br[0][0], hf, acc[0], 0, 0, 0);
            acc[1] = __builtin_amdgcn_mfma_f32_16x16x32_bf16(Br[0][1], hf, acc[1], 0, 0, 0);
            hf = *(const short8*)&hslc[fo[1] + fro];
            acc[0] = __builtin_amdgcn_mfma_f32_16x16x32_bf16(Br[1][0], hf, acc[0], 0, 0, 0);
            acc[1] = __builtin_amdgcn_mfma_f32_16x16x32_bf16(Br[1][1], hf, acc[1], 0, 0, 0);
        }

        // wait for 3 partners; scatter their h into slice-layout
        if (t > 0) {
            const unsigned long long tt = (unsigned long long)(unsigned)t
                                        | ((unsigned long long)(unsigned)t << 32);
            for (;;) {
                const unsigned long long bad = (pw0 ^ tt) | (pw1 ^ tt) | (pw2 ^ tt);
                if ((bad & 0x0000ffff0000ffffULL) == 0ULL) break;
                pw0 = __hip_atomic_load(ps0, __ATOMIC_RELAXED, __HIP_MEMORY_SCOPE_AGENT);
                pw1 = __hip_atomic_load(ps1, __ATOMIC_RELAXED, __HIP_MEMORY_SCOPE_AGENT);
                pw2 = __hip_atomic_load(ps2, __ATOMIC_RELAXED, __HIP_MEMORY_SCOPE_AGENT);
            }
            hslc[sf[0][0]] = (unsigned short)(pw0 >> 16);
            hslc[sf[0][1]] = (unsigned short)(pw0 >> 48);
            hslc[sf[1][0]] = (unsigned short)(pw1 >> 16);
            hslc[sf[1][1]] = (unsigned short)(pw1 >> 48);
            hslc[sf[2][0]] = (unsigned short)(pw2 >> 16);
            hslc[sf[2][1]] = (unsigned short)(pw2 >> 48);
        }
        __syncthreads();

        // partner K-slices: Br[2..7]
        #pragma unroll
        for (int j = 2; j < 8; ++j) {
            short8 hf = *(const short8*)&hslc[fo[j] + fro];
            acc[0] = __builtin_amdgcn_mfma_f32_16x16x32_bf16(Br[j][0], hf, acc[0], 0, 0, 0);
            acc[1] = __builtin_amdgcn_mfma_f32_16x16x32_bf16(Br[j][1], hf, acc[1], 0, 0, 0);
        }

        // gates: acc[m][r] = gate r of (unit u_m, batch ln)
        float h0, h1;
        {
            float vf = acc[0][0] + b2f(xlc[xb[0]]);
            float vi = acc[0][1] + b2f(xlc[xb[0] + 64]);
            float vc = acc[0][2] + b2f(xlc[xb[0] + 128]);
            float vo = acc[0][3] + b2f(xlc[xb[0] + 192]);
            float ea = __expf(-vf), ei = __expf(-vi);
            float eb = __expf(-2.0f * vc), eo = __expf(-vo);
            float rf = __builtin_amdgcn_rcpf(1.0f + ea);
            float it = (1.0f - eb) * __builtin_amdgcn_rcpf((1.0f + ei) * (1.0f + eb));
            float cn = fmaf(rf, c0, it);
            c0 = cn;
            float ed = __expf(-2.0f * cn);
            h0 = (1.0f - ed) * __builtin_amdgcn_rcpf((1.0f + eo) * (1.0f + ed));
        }
        {
            float vf = acc[1][0] + b2f(xlc[xb[1]]);
            float vi = acc[1][1] + b2f(xlc[xb[1] + 64]);
            float vc = acc[1][2] + b2f(xlc[xb[1] + 128]);
            float vo = acc[1][3] + b2f(xlc[xb[1] + 192]);
            float ea = __expf(-vf), ei = __expf(-vi);
            float eb = __expf(-2.0f * vc), eo = __expf(-vo);
            float rf = __builtin_amdgcn_rcpf(1.0f + ea);
            float it = (1.0f - eb) * __builtin_amdgcn_rcpf((1.0f + ei) * (1.0f + eb));
            float cn = fmaf(rf, c1, it);
            c1 = cn;
            float ed = __expf(-2.0f * cn);
            h1 = (1.0f - ed) * __builtin_amdgcn_rcpf((1.0f + eo) * (1.0f + ed));
        }
        // pack both h to bf16 (RNE) in one op; store local + publish u64
        unsigned int p;
        asm("v_cvt_pk_bf16_f32 %0, %1, %2" : "=v"(p) : "v"(h0), "v"(h1));
        hsln[ho[0]] = (unsigned short)p;
        hsln[ho[1]] = (unsigned short)(p >> 16);
        const unsigned int tagn = (unsigned int)(t + 1);
        const unsigned long long pubv =
            (unsigned long long)((p << 16) | tagn)
            | ((unsigned long long)((p & 0xffff0000u) | tagn) << 32);
        __hip_atomic_store((unsigned long long*)hx64 + pub[cur], pubv,
                           __ATOMIC_RELAXED, __HIP_MEMORY_SCOPE_AGENT);

        // stage next xp tile (buffer not read this step)
        if (do_stage) *(short8*)&xln[xdst] = sv;
        __syncthreads();
    }

    // epilogue: own 64 units of h(511) live in hsl0 (t=511 wrote parity 0)
    if (tid < 32) {
        const int r = tid >> 1, o = tid & 1;
        float acc_fc = (Q == 0) ? fc_b[o] : 0.0f;
        for (int jj = 0; jj < 64; ++jj) {
            const int ug = Q * 64 + jj;
            const int ss = ug >> 5, k = ug & 31;
            float h = b2f(hsl0[ss * 512 + ((k >> 3) * 16 + r) * 8 + (k & 7)]);
            acc_fc += h * fc_w[o * HID + ug];
        }
        atomicAdd(&out[(16 * g + r) * 2 + o], acc_fc);
    }
}

extern "C" void kernel_launch(void* const* d_in, const int* in_sizes, int n_in,
                              void* d_out, int out_size, void* d_ws, size_t ws_size,
                              hipStream_t stream) {
    const int*   tokens = (const int*)  d_in[0];
    const float* emb    = (const float*)d_in[1];
    const float* W_x    = (const float*)d_in[2];
    const float* b_x    = (const float*)d_in[3];
    const float* U_h    = (const float*)d_in[4];
    const float* b_u    = (const float*)d_in[5];
    const float* b_g    = (const float*)d_in[6];
    const float* fc_w   = (const float*)d_in[7];
    const float* fc_b   = (const float*)d_in[8];
    float* out = (float*)d_out;

    char* ws = (char*)d_ws;
    unsigned short* w_xb  = (unsigned short*)(ws);                 // 512 KB
    unsigned short* u_hb  = (unsigned short*)(ws + 524288);        // 512 KB
    float*          bias  = (float*)(ws + 1048576);                // 4 KB
    unsigned int*   hxw   = (unsigned int*)(ws + 1052672);         // 256 KB [2][8][4][512] u32x2
    unsigned short* xp    = (unsigned short*)(ws + 1314816);       // 128 MB bf16 [S][B][4H]

    prep_kernel<<<1024, 256, 0, stream>>>(W_x, U_h, b_x, b_u, b_g, w_xb, u_hb, bias,
                                          hxw, out);
    xp_gemm<<<1024, 256, 0, stream>>>(tokens, emb, w_xb, bias, xp);

    lstm_recur<<<32, 512, 0, stream>>>(xp, u_hb, fc_w, fc_b, hxw, out);
}

// Round 15
// 664.375 us; speedup vs baseline: 2.3588x; 1.1794x over previous
//
#include <hip/hip_runtime.h>

typedef short short8 __attribute__((ext_vector_type(8)));
typedef float f4 __attribute__((ext_vector_type(4)));

#define BATCH 128
#define SEQ   512
#define EMB   256
#define HID   256
#define G4    1024   // 4*HID

static __device__ __forceinline__ unsigned short f2b(float f) {
    union { float f; unsigned int u; } v; v.f = f;
    unsigned int u = v.u;
    return (unsigned short)((u + 0x7FFFu + ((u >> 16) & 1u)) >> 16);  // RNE
}
static __device__ __forceinline__ float b2f(unsigned short s) {
    union { unsigned int u; float f; } v; v.u = ((unsigned int)s) << 16;
    return v.f;
}

// ---------------- Kernel 0: convert weights, fold biases, zero sync state -------
__global__ void prep_kernel(const float* __restrict__ W_x, const float* __restrict__ U_h,
                            const float* __restrict__ b_x, const float* __restrict__ b_u,
                            const float* __restrict__ b_g,
                            unsigned short* __restrict__ w_xb, unsigned short* __restrict__ u_hb,
                            float* __restrict__ bias,
                            unsigned int* __restrict__ hx32, float* __restrict__ out) {
    int i = blockIdx.x * blockDim.x + threadIdx.x;
    if (i < G4 * EMB) w_xb[i] = f2b(W_x[i]);
    if (i < G4 * HID) u_hb[i] = f2b(U_h[i]);
    if (i < G4) bias[i] = b_x[i] + b_u[i] + b_g[i];
    if (i < 65536) hx32[i] = 0;      // tag=0 everywhere (re-zeroed EVERY launch)
    if (i < 256) out[i] = 0.0f;      // out is atomicAdd-accumulated
}

// ---------------- Kernel 1: xp[s][b][g] = emb[tokens[b,s]] @ W_x^T + bias --------
__global__ __launch_bounds__(256) void xp_gemm(
    const int* __restrict__ tokens, const float* __restrict__ emb,
    const unsigned short* __restrict__ w_xb, const float* __restrict__ bias,
    unsigned short* __restrict__ xp)
{
    __shared__ unsigned short As[64][264];   // A tile
    __shared__ unsigned short Bs[64][264];   // staged B slice
    __shared__ unsigned short Xs[64][72];    // store-transpose bounce
    const int m0 = blockIdx.x * 64;
    const int b  = m0 >> 9;          // m0 / SEQ
    const int s0 = m0 & 511;         // m0 % SEQ
    const int tid = threadIdx.x;
    const int cS = tid >> 2, qS = (tid & 3) * 64;   // staging map (A and B)
    {
        const int tok = tokens[m0 + cS];
        const float* src = emb + (long)tok * EMB + qS;
        #pragma unroll
        for (int i = 0; i < 8; ++i) {
            float4 v0 = ((const float4*)src)[2 * i];
            float4 v1 = ((const float4*)src)[2 * i + 1];
            short8 pk;
            pk[0] = (short)f2b(v0.x); pk[1] = (short)f2b(v0.y);
            pk[2] = (short)f2b(v0.z); pk[3] = (short)f2b(v0.w);
            pk[4] = (short)f2b(v1.x); pk[5] = (short)f2b(v1.y);
            pk[6] = (short)f2b(v1.z); pk[7] = (short)f2b(v1.w);
            *(short8*)&As[cS][qS + i * 8] = pk;
        }
    }
    __syncthreads();
    const int w = tid >> 6, l = tid & 63;
    const int ln = l & 15, hi = l >> 4;
    short8 a[8];
    #pragma unroll
    for (int kk = 0; kk < 8; ++kk)
        a[kk] = *(const short8*)&As[16 * w + ln][kk * 32 + hi * 8];

    const int rl = tid >> 2;            // global-store row (own wave's rows)
    const int cl = (tid & 3) * 16;      // global-store col offset in 64-tile

    for (int n0 = 0; n0 < G4; n0 += 64) {
        {
            const unsigned short* src = &w_xb[(size_t)(n0 + cS) * EMB + qS];
            #pragma unroll
            for (int i = 0; i < 8; ++i)
                *(short8*)&Bs[cS][qS + i * 8] = *(const short8*)&src[i * 8];
        }
        __syncthreads();
        f4 acc[4] = {};
        #pragma unroll
        for (int kk = 0; kk < 8; ++kk) {
            #pragma unroll
            for (int nn = 0; nn < 4; ++nn) {
                short8 bfr = *(const short8*)&Bs[nn * 16 + ln][kk * 32 + hi * 8];
                acc[nn] = __builtin_amdgcn_mfma_f32_16x16x32_bf16(a[kk], bfr, acc[nn], 0, 0, 0);
            }
        }
        #pragma unroll
        for (int nn = 0; nn < 4; ++nn) {
            const float bs = bias[n0 + nn * 16 + ln];
            #pragma unroll
            for (int r = 0; r < 4; ++r)
                Xs[16 * w + 4 * hi + r][nn * 16 + ln] = f2b(acc[nn][r] + bs);
        }
        size_t off = ((size_t)(s0 + rl) * BATCH + b) * G4 + n0 + cl;
        *(short8*)&xp[off]     = *(const short8*)&Xs[rl][cl];
        *(short8*)&xp[off + 8] = *(const short8*)&Xs[rl][cl + 8];
        __syncthreads();
    }
}

// ---------------- Kernel 2: LSTM, 64 blocks = 8 groups x 8 eighths, 512 thr -----
// Block (g=bid&7, E=bid>>3): batch rows 16g..+16, units E*32..+32, all 4 gates.
// Swapped-operand MFMA, unit-major/gate-minor reorder => lane (w,hi,ln) owns the
// full cell (unit lu=w*4+hi, batch ln): acc[r] = gate r. Br[8] = 32 regs (AGPR).
// Exchange: tagged-word protocol, 7 partners x 1 u32 poll/thread; parity dbuf;
// publish-after-poll full graph => no ABA (same argument as 4-way, r13).
// hxw layout: [2 par][8 g][8 E][512 cells], cell = lu*16 + batch.
__global__ void __launch_bounds__(512, 2)
lstm_recur(const unsigned short* __restrict__ xp,
           const unsigned short* __restrict__ u_hb,
           const float* __restrict__ fc_w, const float* __restrict__ fc_b,
           unsigned int* __restrict__ hxw, float* __restrict__ out)
{
    __shared__ unsigned short hsl0[4096];      // h slice-layout, parity 0: [8 s][512]
    __shared__ unsigned short hsl1[4096];      // parity 1
    __shared__ unsigned short xl0[16 * 136];   // xp tile [batch][4 gate][32 u], 136-pad
    __shared__ unsigned short xl1[16 * 136];
    const int tid = threadIdx.x;
    const int w = tid >> 6, l = tid & 63;
    const int ln = l & 15, hi = l >> 4;
    const int bid = blockIdx.x;
    const int g = bid & 7, E = bid >> 3;
    const int lu = w * 4 + hi;                 // own unit within eighth [0,32)

    // A-frags, rotated slice order: Br[j] = slice (E+j)&7; own slice = j=0.
    short8 Br[8];
    int fo[8];
    {
        const int col = (ln & 3) * 256 + E * 32 + w * 4 + (ln >> 2);
        const unsigned short* ubase = u_hb + (size_t)col * HID + hi * 8;
        #pragma unroll
        for (int j = 0; j < 8; ++j) {
            const int s = (E + j) & 7;
            fo[j] = s * 512;
            Br[j] = *(const short8*)&ubase[s * 32];
        }
    }

    // zero both h slice buffers (h(-1) = 0)
    for (int i = tid; i < 2048; i += 512) { ((unsigned*)hsl0)[i] = 0; ((unsigned*)hsl1)[i] = 0; }

    // xp staging: 512 thr x 8 B: row=tid>>5, seg4=tid&31 (gate=seg4>>3, k=seg4&7)
    const int xrow = tid >> 5, seg4 = tid & 31;
    const size_t xoff = (size_t)(16 * g + xrow) * 1024 + (seg4 >> 3) * 256 + E * 32 + (seg4 & 7) * 4;
    const int xdst = xrow * 136 + (seg4 >> 3) * 32 + (seg4 & 7) * 4;
    *(unsigned long long*)&xl0[xdst] = *(const unsigned long long*)(xp + xoff);
    __syncthreads();

    // ---- hoisted loop-invariant offsets ----
    int pbase[2], pub[2];
    #pragma unroll
    for (int par = 0; par < 2; ++par) {
        pbase[par] = ((par * 8 + g) * 8) * 512 + tid;            // poll: + pq*512
        pub[par]   = ((par * 8 + g) * 8 + E) * 512 + lu * 16 + ln;
    }
    int ppq[7];
    #pragma unroll
    for (int d = 0; d < 7; ++d) ppq[d] = (((E + 1 + d) & 7) << 9);
    // scatter dest within partner slice region (import cell: lu'=tid>>4, b'=tid&15)
    const int lup = tid >> 4, bp = tid & 15;
    const int sbase = ((lup >> 3) * 16 + bp) * 8 + (lup & 7);
    // own h dest + xp gate-read base
    const int ho = E * 512 + ((lu >> 3) * 16 + ln) * 8 + (lu & 7);
    const int xb = ln * 136 + lu;
    const int fro = l * 8;

    float c0 = 0.0f;

    for (int t = 0; t < SEQ; ++t) {
        const int cur = t & 1;
        unsigned short* hslc = cur ? hsl1 : hsl0;    // h(t-1), frag layout
        unsigned short* hsln = cur ? hsl0 : hsl1;    // h(t) dest
        const unsigned short* xlc = cur ? xl1 : xl0;
        unsigned short* xln = cur ? xl0 : xl1;

        // issue 7 partner polls first (oldest in VMEM queue)
        unsigned int pw[7];
        const unsigned int* ps = hxw;
        if (t > 0) {
            ps = hxw + pbase[cur ^ 1];
            #pragma unroll
            for (int d = 0; d < 7; ++d)
                pw[d] = __hip_atomic_load(ps + ppq[d], __ATOMIC_RELAXED, __HIP_MEMORY_SCOPE_AGENT);
        }
        // prefetch next xp chunk
        unsigned long long sv;
        const bool do_stage = (t + 1 < SEQ);
        if (do_stage) sv = *(const unsigned long long*)(xp + (size_t)(t + 1) * 131072 + xoff);

        // own slice (j=0): own-eighth h written by us last step
        f4 acc = {};
        {
            short8 hf = *(const short8*)&hslc[fo[0] + fro];
            acc = __builtin_amdgcn_mfma_f32_16x16x32_bf16(Br[0], hf, acc, 0, 0, 0);
        }

        // wait for 7 partners; scatter their h into slice layout
        if (t > 0) {
            const unsigned int tag = (unsigned int)t;
            for (;;) {
                unsigned int bad = 0;
                #pragma unroll
                for (int d = 0; d < 7; ++d) bad |= (pw[d] ^ tag);
                if ((bad & 0xffffu) == 0u) break;
                #pragma unroll
                for (int d = 0; d < 7; ++d)
                    pw[d] = __hip_atomic_load(ps + ppq[d], __ATOMIC_RELAXED, __HIP_MEMORY_SCOPE_AGENT);
            }
            #pragma unroll
            for (int d = 0; d < 7; ++d)
                hslc[ppq[d] + sbase] = (unsigned short)(pw[d] >> 16);
        }
        __syncthreads();

        // partner slices j=1..7
        #pragma unroll
        for (int j = 1; j < 8; ++j) {
            short8 hf = *(const short8*)&hslc[fo[j] + fro];
            acc = __builtin_amdgcn_mfma_f32_16x16x32_bf16(Br[j], hf, acc, 0, 0, 0);
        }

        // gates: acc[r] = gate r of (unit lu, batch ln)
        float vf = acc[0] + b2f(xlc[xb]);
        float vi = acc[1] + b2f(xlc[xb + 32]);
        float vc = acc[2] + b2f(xlc[xb + 64]);
        float vo = acc[3] + b2f(xlc[xb + 96]);
        float ea = __expf(-vf), ei = __expf(-vi);
        float eb = __expf(-2.0f * vc), eo = __expf(-vo);
        float rf = __builtin_amdgcn_rcpf(1.0f + ea);
        float it = (1.0f - eb) * __builtin_amdgcn_rcpf((1.0f + ei) * (1.0f + eb));
        float cn = fmaf(rf, c0, it);
        c0 = cn;
        float ed = __expf(-2.0f * cn);
        float h = (1.0f - ed) * __builtin_amdgcn_rcpf((1.0f + eo) * (1.0f + ed));
        unsigned short hb16 = f2b(h);
        hsln[ho] = hb16;
        __hip_atomic_store(hxw + pub[cur], ((unsigned int)hb16 << 16) | (unsigned int)(t + 1),
                           __ATOMIC_RELAXED, __HIP_MEMORY_SCOPE_AGENT);

        // stage next xp tile (buffer not read this step)
        if (do_stage) *(unsigned long long*)&xln[xdst] = sv;
        __syncthreads();
    }

    // epilogue: own 32 units of h(511) live in hsl0 (t=511 wrote parity 0)
    if (tid < 32) {
        const int r = tid >> 1, o = tid & 1;
        float acc_fc = (E == 0) ? fc_b[o] : 0.0f;
        for (int jj = 0; jj < 32; ++jj) {
            float h = b2f(hsl0[E * 512 + ((jj >> 3) * 16 + r) * 8 + (jj & 7)]);
            acc_fc += h * fc_w[o * HID + E * 32 + jj];
        }
        atomicAdd(&out[(16 * g + r) * 2 + o], acc_fc);
    }
}

extern "C" void kernel_launch(void* const* d_in, const int* in_sizes, int n_in,
                              void* d_out, int out_size, void* d_ws, size_t ws_size,
                              hipStream_t stream) {
    const int*   tokens = (const int*)  d_in[0];
    const float* emb    = (const float*)d_in[1];
    const float* W_x    = (const float*)d_in[2];
    const float* b_x    = (const float*)d_in[3];
    const float* U_h    = (const float*)d_in[4];
    const float* b_u    = (const float*)d_in[5];
    const float* b_g    = (const float*)d_in[6];
    const float* fc_w   = (const float*)d_in[7];
    const float* fc_b   = (const float*)d_in[8];
    float* out = (float*)d_out;

    char* ws = (char*)d_ws;
    unsigned short* w_xb  = (unsigned short*)(ws);                 // 512 KB
    unsigned short* u_hb  = (unsigned short*)(ws + 524288);        // 512 KB
    float*          bias  = (float*)(ws + 1048576);                // 4 KB
    unsigned int*   hxw   = (unsigned int*)(ws + 1052672);         // 256 KB [2][8][8][512] u32
    unsigned short* xp    = (unsigned short*)(ws + 1314816);       // 128 MB bf16 [S][B][4H]

    prep_kernel<<<1024, 256, 0, stream>>>(W_x, U_h, b_x, b_u, b_g, w_xb, u_hb, bias,
                                          hxw, out);
    xp_gemm<<<1024, 256, 0, stream>>>(tokens, emb, w_xb, bias, xp);

    lstm_recur<<<64, 512, 0, stream>>>(xp, u_hb, fc_w, fc_b, hxw, out);
}